// Round 1
// 620.185 us; speedup vs baseline: 1.0524x; 1.0524x over previous
//
#include <hip/hip_runtime.h>
#include <hip/hip_bf16.h>
#include <math.h>

// Problem constants (from reference)
#define Bq   4
#define Tq   512
#define Hq   512
#define Vq   32000
#define Sq   512
#define SDVq 300
#define TDVq 512
#define ROWS (Bq * Tq)            // 2048
#define OUTW (Vq + SDVq + TDVq)   // 32812

typedef __bf16 bf16x8 __attribute__((ext_vector_type(8)));
typedef float  fx4    __attribute__((ext_vector_type(4)));

__device__ __forceinline__ void async16(const void* g, void* l) {
    __builtin_amdgcn_global_load_lds(
        (const __attribute__((address_space(1))) void*)g,
        (__attribute__((address_space(3))) void*)l, 16, 0, 0);
}

// -------------------------------------------------------------------------
// K1: p = softmax(h @ Wp + bp) per row; one wave per row.
// Also zeroes rowsum[row] (consumed by gemm epilogue atomics).
__global__ void compute_p(const float* __restrict__ hiddens,
                          const float* __restrict__ Wp,
                          const float* __restrict__ bp,
                          float* __restrict__ p,
                          float* __restrict__ rowsum) {
    int row  = blockIdx.x;
    int lane = threadIdx.x;   // 64 lanes
    if (lane == 0) rowsum[row] = 0.f;
    const float* h = hiddens + (size_t)row * Hq;
    float a0 = 0.f, a1 = 0.f, a2 = 0.f;
    for (int i = lane; i < Hq; i += 64) {
        float hv = h[i];
        a0 += hv * Wp[i * 3 + 0];
        a1 += hv * Wp[i * 3 + 1];
        a2 += hv * Wp[i * 3 + 2];
    }
    for (int off = 32; off > 0; off >>= 1) {
        a0 += __shfl_down(a0, off);
        a1 += __shfl_down(a1, off);
        a2 += __shfl_down(a2, off);
    }
    if (lane == 0) {
        float l0 = a0 + bp[0], l1 = a1 + bp[1], l2 = a2 + bp[2];
        float M  = fmaxf(l0, fmaxf(l1, l2));
        float e0 = expf(l0 - M), e1 = expf(l1 - M), e2 = expf(l2 - M);
        float inv = 1.f / (e0 + e1 + e2);
        p[row * 3 + 0] = e0 * inv;
        p[row * 3 + 1] = e1 * inv;
        p[row * 3 + 2] = e2 * inv;
    }
}

// -------------------------------------------------------------------------
// K2: extract one-hot index per map row (argmax). One wave per row.
__global__ void extract_idx(const float* __restrict__ map, int ncols,
                            int* __restrict__ idx) {
    int row  = blockIdx.x;
    int lane = threadIdx.x;
    const float* r = map + (size_t)row * ncols;
    float best = -1.f; int bi = 0;
    for (int i = lane; i < ncols; i += 64) {
        float v = r[i];
        if (v > best) { best = v; bi = i; }
    }
    for (int off = 32; off > 0; off >>= 1) {
        float ob  = __shfl_down(best, off);
        int   obi = __shfl_down(bi, off);
        if (ob > best) { best = ob; bi = obi; }
    }
    if (lane == 0) idx[row] = bi;
}

// -------------------------------------------------------------------------
// Conversion: hiddens fp32 -> bf16 (same layout, k contiguous)
__global__ __launch_bounds__(256)
void convert_a(const float* __restrict__ in, __hip_bfloat16* __restrict__ o) {
    int i = blockIdx.x * 256 + threadIdx.x;
    float4 v = ((const float4*)in)[i];
    __hip_bfloat16* op = o + (size_t)i * 4;
    op[0] = __float2bfloat16(v.x);
    op[1] = __float2bfloat16(v.y);
    op[2] = __float2bfloat16(v.z);
    op[3] = __float2bfloat16(v.w);
}

// Transpose+convert: Wv (512 x 32000 fp32) -> Wt (32000 x 512 bf16)
__global__ __launch_bounds__(256)
void transpose_wv(const float* __restrict__ Wv, __hip_bfloat16* __restrict__ Wt) {
    __shared__ float t[32][33];
    int n0 = blockIdx.x * 32, k0 = blockIdx.y * 32;
    int tx = threadIdx.x, ty = threadIdx.y;   // 32 x 8
#pragma unroll
    for (int r = 0; r < 4; ++r)
        t[ty + r * 8][tx] = Wv[(size_t)(k0 + ty + r * 8) * Vq + n0 + tx];
    __syncthreads();
#pragma unroll
    for (int r = 0; r < 4; ++r)
        Wt[(size_t)(n0 + ty + r * 8) * Hq + k0 + tx] =
            __float2bfloat16(t[tx][ty + r * 8]);
}

// -------------------------------------------------------------------------
// K3: bf16 MFMA GEMM, 128x128 tile, BK=32, pipelined (3-deep LDS ring,
// counted vmcnt(4), single raw s_barrier per K-step) — loads for tile t+1
// stay in flight across the barrier instead of the full __syncthreads drain.
// Epilogue fused: e = exp(score + bv) (col 0 -> 0), stored to out, per-row
// partial sums reduced (shfl_xor within 16-lane groups -> LDS -> one global
// atomicAdd per row per block). exp without max-subtraction is safe here:
// scores ~ N(0,1) (Wv scaled 1/sqrt(H)), and softmax is shift-invariant.
__global__ __launch_bounds__(256)
void gemm_mfma(const __hip_bfloat16* __restrict__ A,
               const __hip_bfloat16* __restrict__ Bt,
               const float* __restrict__ bv,
               float* __restrict__ out,
               float* __restrict__ rowsum) {
    __shared__ __align__(16) unsigned short As[3 * 4096];   // 24 KB (3 bufs)
    __shared__ __align__(16) unsigned short Bs[3 * 4096];   // 24 KB
    __shared__ float rs[128];
    int tid  = threadIdx.x;
    int wave = tid >> 6, lane = tid & 63;
    int bm = blockIdx.x * 128;   // 16 m-blocks
    int bn = blockIdx.y * 128;   // 250 n-blocks
    int wr = wave >> 1, wc = wave & 1;
    int lr = lane & 15;          // fragment row/col within 16
    int kq = lane >> 4;          // k-quad (0..3)

    fx4 acc[4][4];
#pragma unroll
    for (int i = 0; i < 4; ++i)
#pragma unroll
        for (int j = 0; j < 4; ++j)
            acc[i][j] = (fx4){0.f, 0.f, 0.f, 0.f};

    // staging chunk ids: chunk c covers row=c&127, kchunk=c>>7 (16B each)
    int c0 = tid, c1 = tid + 256;
    int ar0 = c0 & 127, ak0 = (c0 >> 7) * 8;
    int ar1 = c1 & 127, ak1 = (c1 >> 7) * 8;
    const unsigned short* Ag = (const unsigned short*)A;
    const unsigned short* Bg = (const unsigned short*)Bt;

    // stage K-tile tt (k0 = tt*32) into ring buffer bb (0..2).
    // LDS dest is wave-uniform base + lane*16B (global_load_lds semantics);
    // layout [kchunk(4)][row(128)][8 bf16] per buffer.
#define STAGE(tt, bb) do {                                                   \
        int k0s = (tt) * 32;                                                 \
        unsigned short* Ab = &As[(bb) * 4096 + (wave << 6) * 8];             \
        unsigned short* Bb = &Bs[(bb) * 4096 + (wave << 6) * 8];             \
        async16(Ag + (size_t)(bm + ar0) * Hq + k0s + ak0, Ab);               \
        async16(Ag + (size_t)(bm + ar1) * Hq + k0s + ak1, Ab + 2048);        \
        async16(Bg + (size_t)(bn + ar0) * Hq + k0s + ak0, Bb);               \
        async16(Bg + (size_t)(bn + ar1) * Hq + k0s + ak1, Bb + 2048);        \
    } while (0)

    STAGE(0, 0);
    STAGE(1, 1);

#pragma unroll
    for (int t = 0; t < 16; ++t) {
        // drain my own stage(t) (4 oldest loads); leave stage(t+1) in flight
        if (t < 15) asm volatile("s_waitcnt vmcnt(4)" ::: "memory");
        else        asm volatile("s_waitcnt vmcnt(0)" ::: "memory");
        __builtin_amdgcn_s_barrier();
        asm volatile("" ::: "memory");   // no LDS ops hoist above the barrier

        const unsigned short* Asb = &As[(t % 3) * 4096];
        const unsigned short* Bsb = &Bs[(t % 3) * 4096];
        bf16x8 af[4], bfr[4];
#pragma unroll
        for (int i = 0; i < 4; ++i)
            af[i] = *(const bf16x8*)&Asb[(size_t)(kq * 128 + wr * 64 + i * 16 + lr) * 8];
#pragma unroll
        for (int j = 0; j < 4; ++j)
            bfr[j] = *(const bf16x8*)&Bsb[(size_t)(kq * 128 + wc * 64 + j * 16 + lr) * 8];

        if (t + 2 < 16) STAGE(t + 2, (t + 2) % 3);

#pragma unroll
        for (int i = 0; i < 4; ++i)
#pragma unroll
            for (int j = 0; j < 4; ++j)
                acc[i][j] = __builtin_amdgcn_mfma_f32_16x16x32_bf16(
                    af[i], bfr[j], acc[i][j], 0, 0, 0);

        // all my ds_reads complete before the next barrier lets anyone's
        // DMA overwrite this ring slot (slot t%3 is rewritten at iter t+1)
        asm volatile("s_waitcnt lgkmcnt(0)" ::: "memory");
    }
#undef STAGE

    // ---------------- fused epilogue: e = exp(score + bias), row sums ----
    if (tid < 128) rs[tid] = 0.f;
    __syncthreads();

    float bvv[4];
#pragma unroll
    for (int j = 0; j < 4; ++j)
        bvv[j] = bv[bn + wc * 64 + j * 16 + lr];

    // C/D layout: col = lane&15, row = (lane>>4)*4 + reg
#pragma unroll
    for (int i = 0; i < 4; ++i) {
        int lrow = wr * 64 + i * 16 + kq * 4;   // local row base of regs r=0..3
        float rsum[4] = {0.f, 0.f, 0.f, 0.f};
#pragma unroll
        for (int j = 0; j < 4; ++j) {
            int gc = bn + wc * 64 + j * 16 + lr;
#pragma unroll
            for (int r = 0; r < 4; ++r) {
                float v = __expf(acc[i][j][r] + bvv[j]);
                if (gc == 0) v = 0.f;   // scores[:,0] = -inf -> e = 0
                out[(size_t)(bm + lrow + r) * OUTW + gc] = v;
                rsum[r] += v;
            }
        }
        // reduce over the 16 lanes (lr) of this kq group
#pragma unroll
        for (int off = 1; off < 16; off <<= 1) {
#pragma unroll
            for (int r = 0; r < 4; ++r)
                rsum[r] += __shfl_xor(rsum[r], off);
        }
        if (lr == 0) {
#pragma unroll
            for (int r = 0; r < 4; ++r)
                atomicAdd(&rs[lrow + r], rsum[r]);
        }
    }
    __syncthreads();
    if (tid < 128) atomicAdd(&rowsum[bm + tid], rs[tid]);
}

// -------------------------------------------------------------------------
// K4: single-pass scale of the vocab region: prob = e * pgen / rowsum.
// Fused vocab argmax (e is a positive monotone transform of prob).
__global__ __launch_bounds__(256)
void scale_rows(float* __restrict__ out, const float* __restrict__ rowsum,
                const float* __restrict__ p,
                float* __restrict__ cval, int* __restrict__ cidx) {
    int row = blockIdx.x;
    int tid = threadIdx.x;
    float* rp = out + (size_t)row * OUTW;
    float scale = p[row * 3 + 2] / rowsum[row];   // pgen / sum(e)

    const float4* rv = (const float4*)rp;
    float4* wv = (float4*)rp;
    float bm_ = -1.f; int bi = 0;                 // e > 0 except col 0
    for (int i = tid; i < Vq / 4; i += 256) {
        float4 v = rv[i];
        if (v.x > bm_) { bm_ = v.x; bi = i * 4 + 0; }
        if (v.y > bm_) { bm_ = v.y; bi = i * 4 + 1; }
        if (v.z > bm_) { bm_ = v.z; bi = i * 4 + 2; }
        if (v.w > bm_) { bm_ = v.w; bi = i * 4 + 3; }
        v.x *= scale; v.y *= scale; v.z *= scale; v.w *= scale;
        wv[i] = v;
    }
    __shared__ float bs[256];
    __shared__ int   is_[256];
    bs[tid] = bm_; is_[tid] = bi;
    __syncthreads();
    for (int s = 128; s > 0; s >>= 1) {
        if (tid < s) {
            float v2 = bs[tid + s]; int i2 = is_[tid + s];
            if (v2 > bs[tid] || (v2 == bs[tid] && i2 < is_[tid])) {
                bs[tid] = v2; is_[tid] = i2;
            }
        }
        __syncthreads();
    }
    if (tid == 0) { cval[row * 3] = bs[0] * scale; cidx[row * 3] = is_[0]; }
}

// -------------------------------------------------------------------------
// K5: scatter-add copy distribution + fused region argmax -> candidate slot.
__global__ __launch_bounds__(256)
void copy_scatter(const float* __restrict__ att, const int* __restrict__ idx,
                  const float* __restrict__ p, int pcol, int slot,
                  int natt, int nout, float* __restrict__ out, int out_off,
                  float* __restrict__ cval, int* __restrict__ cidx) {
    int row = blockIdx.x;       // b*T + t
    int b   = row >> 9;         // /512
    int tid = threadIdx.x;
    __shared__ float acc[TDVq];
    for (int i = tid; i < nout; i += 256) acc[i] = 0.f;
    __syncthreads();
    const float* arow = att + (size_t)row * natt;
    const int*   ib   = idx + b * natt;
    for (int s = tid; s < natt; s += 256) {
        atomicAdd(&acc[ib[s]], arow[s]);
    }
    __syncthreads();
    float pc = p[row * 3 + pcol];
    float* orow = out + (size_t)row * OUTW + out_off;
    float bm_ = -INFINITY; int bi = 0;
    for (int v = tid; v < nout; v += 256) {
        float val = acc[v] * pc;
        orow[v] = val;
        if (val > bm_) { bm_ = val; bi = v; }
    }
    __shared__ float bs[256];
    __shared__ int   is_[256];
    bs[tid] = bm_; is_[tid] = bi;
    __syncthreads();
    for (int s = 128; s > 0; s >>= 1) {
        if (tid < s) {
            float v2 = bs[tid + s]; int i2 = is_[tid + s];
            if (v2 > bs[tid] || (v2 == bs[tid] && i2 < is_[tid])) {
                bs[tid] = v2; is_[tid] = i2;
            }
        }
        __syncthreads();
    }
    if (tid == 0) { cval[row * 3 + slot] = bs[0]; cidx[row * 3 + slot] = out_off + is_[0]; }
}

// -------------------------------------------------------------------------
// K6: combine 3 per-region argmax candidates -> predictions (as float).
__global__ void combine_pred(const float* __restrict__ cval,
                             const int* __restrict__ cidx,
                             float* __restrict__ pred) {
    int r = blockIdx.x * 256 + threadIdx.x;
    if (r >= ROWS) return;
    float v = cval[r * 3]; int i = cidx[r * 3];
    if (cval[r * 3 + 1] > v) { v = cval[r * 3 + 1]; i = cidx[r * 3 + 1]; }
    if (cval[r * 3 + 2] > v) { v = cval[r * 3 + 2]; i = cidx[r * 3 + 2]; }
    pred[r] = (float)i;
}

// -------------------------------------------------------------------------
extern "C" void kernel_launch(void* const* d_in, const int* in_sizes, int n_in,
                              void* d_out, int out_size, void* d_ws, size_t ws_size,
                              hipStream_t stream) {
    const float* hiddens = (const float*)d_in[0];
    const float* Wp      = (const float*)d_in[1];
    const float* bp      = (const float*)d_in[2];
    const float* Wv      = (const float*)d_in[3];
    const float* bv      = (const float*)d_in[4];
    const float* src_att = (const float*)d_in[5];
    const float* src_map = (const float*)d_in[6];
    const float* tgt_att = (const float*)d_in[7];
    const float* tgt_map = (const float*)d_in[8];

    float* out  = (float*)d_out;
    float* pred = out + (size_t)ROWS * OUTW;

    // workspace layout (bytes)
    char* ws = (char*)d_ws;
    float* p_ws   = (float*)(ws);                       // 24 KB
    int*   sidx   = (int*)(ws + (24 << 10));            // 8 KB
    int*   tidx   = (int*)(ws + (32 << 10));            // 8 KB
    float* cval   = (float*)(ws + (40 << 10));          // 24 KB
    int*   cidx   = (int*)(ws + (64 << 10));            // 24 KB
    float* rowsum = (float*)(ws + (88 << 10));          // 8 KB
    __hip_bfloat16* A_bf = (__hip_bfloat16*)(ws + (128 << 10));              // 2 MB
    __hip_bfloat16* Wt   = (__hip_bfloat16*)(ws + (128 << 10) + (2 << 20));  // 32.75 MB

    // conversions
    convert_a<<<ROWS * Hq / 4 / 256, 256, 0, stream>>>(hiddens, A_bf);
    {
        dim3 tg(Vq / 32, Hq / 32);   // (1000, 16)
        dim3 tb(32, 8);
        transpose_wv<<<tg, tb, 0, stream>>>(Wv, Wt);
    }

    // gate probabilities (+ rowsum zeroing) + one-hot indices
    compute_p<<<ROWS, 64, 0, stream>>>(hiddens, Wp, bp, p_ws, rowsum);
    extract_idx<<<Bq * Sq, 64, 0, stream>>>(src_map, SDVq, sidx);
    extract_idx<<<Bq * Tq, 64, 0, stream>>>(tgt_map, TDVq, tidx);

    // GEMM (pipelined) with fused exp+bias epilogue; writes e, accumulates
    // per-row sums into rowsum via atomics.
    {
        dim3 gg(ROWS / 128, Vq / 128);   // (16, 250)
        gemm_mfma<<<gg, 256, 0, stream>>>(A_bf, Wt, bv, out, rowsum);
    }

    // single-pass normalization * p_generate, fused vocab argmax
    scale_rows<<<ROWS, 256, 0, stream>>>(out, rowsum, p_ws, cval, cidx);

    // copy distributions, fused region argmax
    copy_scatter<<<ROWS, 256, 0, stream>>>(src_att, sidx, p_ws, 0, 1, Sq, SDVq,
                                           out, Vq, cval, cidx);
    copy_scatter<<<ROWS, 256, 0, stream>>>(tgt_att, tidx, p_ws, 1, 2, TDVq, TDVq,
                                           out, Vq + SDVq, cval, cidx);

    // predictions
    combine_pred<<<(ROWS + 255) / 256, 256, 0, stream>>>(cval, cidx, pred);
}

// Round 2
// 570.171 us; speedup vs baseline: 1.1447x; 1.0877x over previous
//
#include <hip/hip_runtime.h>
#include <hip/hip_bf16.h>
#include <math.h>

// Problem constants (from reference)
#define Bq   4
#define Tq   512
#define Hq   512
#define Vq   32000
#define Sq   512
#define SDVq 300
#define TDVq 512
#define ROWS (Bq * Tq)            // 2048
#define OUTW (Vq + SDVq + TDVq)   // 32812
#define NBLK (Vq / 128)           // 250 n-panels

typedef __bf16 bf16x8 __attribute__((ext_vector_type(8)));
typedef float  fx4    __attribute__((ext_vector_type(4)));
typedef unsigned short ushort8 __attribute__((ext_vector_type(8)));

__device__ __forceinline__ void async16(const void* g, void* l) {
    __builtin_amdgcn_global_load_lds(
        (const __attribute__((address_space(1))) void*)g,
        (__attribute__((address_space(3))) void*)l, 16, 0, 0);
}

__device__ __forceinline__ float bf2f(unsigned short u) {
    union { unsigned int i; float f; } c;
    c.i = ((unsigned int)u) << 16;
    return c.f;
}

// -------------------------------------------------------------------------
// K1: p = softmax(h @ Wp + bp) per row; one wave per row.
__global__ void compute_p(const float* __restrict__ hiddens,
                          const float* __restrict__ Wp,
                          const float* __restrict__ bp,
                          float* __restrict__ p) {
    int row  = blockIdx.x;
    int lane = threadIdx.x;   // 64 lanes
    const float* h = hiddens + (size_t)row * Hq;
    float a0 = 0.f, a1 = 0.f, a2 = 0.f;
    for (int i = lane; i < Hq; i += 64) {
        float hv = h[i];
        a0 += hv * Wp[i * 3 + 0];
        a1 += hv * Wp[i * 3 + 1];
        a2 += hv * Wp[i * 3 + 2];
    }
    for (int off = 32; off > 0; off >>= 1) {
        a0 += __shfl_down(a0, off);
        a1 += __shfl_down(a1, off);
        a2 += __shfl_down(a2, off);
    }
    if (lane == 0) {
        float l0 = a0 + bp[0], l1 = a1 + bp[1], l2 = a2 + bp[2];
        float M  = fmaxf(l0, fmaxf(l1, l2));
        float e0 = expf(l0 - M), e1 = expf(l1 - M), e2 = expf(l2 - M);
        float inv = 1.f / (e0 + e1 + e2);
        p[row * 3 + 0] = e0 * inv;
        p[row * 3 + 1] = e1 * inv;
        p[row * 3 + 2] = e2 * inv;
    }
}

// -------------------------------------------------------------------------
// K2: extract one-hot index per map row (argmax). One wave per row.
__global__ void extract_idx(const float* __restrict__ map, int ncols,
                            int* __restrict__ idx) {
    int row  = blockIdx.x;
    int lane = threadIdx.x;
    const float* r = map + (size_t)row * ncols;
    float best = -1.f; int bi = 0;
    for (int i = lane; i < ncols; i += 64) {
        float v = r[i];
        if (v > best) { best = v; bi = i; }
    }
    for (int off = 32; off > 0; off >>= 1) {
        float ob  = __shfl_down(best, off);
        int   obi = __shfl_down(bi, off);
        if (ob > best) { best = ob; bi = obi; }
    }
    if (lane == 0) idx[row] = bi;
}

// -------------------------------------------------------------------------
// Conversion: hiddens fp32 -> bf16 (same layout, k contiguous)
__global__ __launch_bounds__(256)
void convert_a(const float* __restrict__ in, __hip_bfloat16* __restrict__ o) {
    int i = blockIdx.x * 256 + threadIdx.x;
    float4 v = ((const float4*)in)[i];
    __hip_bfloat16* op = o + (size_t)i * 4;
    op[0] = __float2bfloat16(v.x);
    op[1] = __float2bfloat16(v.y);
    op[2] = __float2bfloat16(v.z);
    op[3] = __float2bfloat16(v.w);
}

// Transpose+convert: Wv (512 x 32000 fp32) -> Wt (32000 x 512 bf16)
__global__ __launch_bounds__(256)
void transpose_wv(const float* __restrict__ Wv, __hip_bfloat16* __restrict__ Wt) {
    __shared__ float t[32][33];
    int n0 = blockIdx.x * 32, k0 = blockIdx.y * 32;
    int tx = threadIdx.x, ty = threadIdx.y;   // 32 x 8
#pragma unroll
    for (int r = 0; r < 4; ++r)
        t[ty + r * 8][tx] = Wv[(size_t)(k0 + ty + r * 8) * Vq + n0 + tx];
    __syncthreads();
#pragma unroll
    for (int r = 0; r < 4; ++r)
        Wt[(size_t)(n0 + ty + r * 8) * Hq + k0 + tx] =
            __float2bfloat16(t[tx][ty + r * 8]);
}

// -------------------------------------------------------------------------
// K3: bf16 MFMA GEMM, 128x128 tile, BK=32, pipelined (3-deep LDS ring,
// counted vmcnt(4), single raw s_barrier per K-step; next-tile STAGE issues
// right after the barrier so DMA flies under ds_read+MFMA).
// XCD-chunked block swizzle: each XCD owns a contiguous range of n-panels,
// so every B-panel is fetched into exactly one XCD's private L2.
// Epilogue fused: e = exp(score + bv) (col 0 -> 0) stored as BF16 to eb,
// per-row partial sums written NON-atomically to partial[nb][row].
// exp without max-subtraction is safe: scores ~ N(0,1) and softmax is
// shift-invariant.
__global__ __launch_bounds__(256)
void gemm_mfma(const __hip_bfloat16* __restrict__ A,
               const __hip_bfloat16* __restrict__ Bt,
               const float* __restrict__ bv,
               __hip_bfloat16* __restrict__ eb,
               float* __restrict__ partial) {
    __shared__ __align__(16) unsigned short As[3 * 4096];   // 24 KB (3 bufs)
    __shared__ __align__(16) unsigned short Bs[3 * 4096];   // 24 KB
    __shared__ float rs[128];
    int tid  = threadIdx.x;
    int wave = tid >> 6, lane = tid & 63;

    // bijective XCD-chunked swizzle: 4000 blocks, 8 XCDs, 500 per XCD
    int bid = blockIdx.x;
    int logical = (bid & 7) * 500 + (bid >> 3);
    int nb = logical >> 4;          // n-panel (m fastest within an XCD chunk)
    int mb = logical & 15;
    int bm = mb * 128;
    int bn = nb * 128;

    int wr = wave >> 1, wc = wave & 1;
    int lr = lane & 15;          // fragment row/col within 16
    int kq = lane >> 4;          // k-quad (0..3)

    fx4 acc[4][4];
#pragma unroll
    for (int i = 0; i < 4; ++i)
#pragma unroll
        for (int j = 0; j < 4; ++j)
            acc[i][j] = (fx4){0.f, 0.f, 0.f, 0.f};

    // staging chunk ids: chunk c covers row=c&127, kchunk=c>>7 (16B each)
    int c0 = tid, c1 = tid + 256;
    int ar0 = c0 & 127, ak0 = (c0 >> 7) * 8;
    int ar1 = c1 & 127, ak1 = (c1 >> 7) * 8;
    const unsigned short* Ag = (const unsigned short*)A;
    const unsigned short* Bg = (const unsigned short*)Bt;

    // stage K-tile tt (k0 = tt*32) into ring buffer bb (0..2).
    // LDS dest is wave-uniform base + lane*16B (global_load_lds semantics);
    // layout [kchunk(4)][row(128)][8 bf16] per buffer.
#define STAGE(tt, bb) do {                                                   \
        int k0s = (tt) * 32;                                                 \
        unsigned short* Ab = &As[(bb) * 4096 + (wave << 6) * 8];             \
        unsigned short* Bb = &Bs[(bb) * 4096 + (wave << 6) * 8];             \
        async16(Ag + (size_t)(bm + ar0) * Hq + k0s + ak0, Ab);               \
        async16(Ag + (size_t)(bm + ar1) * Hq + k0s + ak1, Ab + 2048);        \
        async16(Bg + (size_t)(bn + ar0) * Hq + k0s + ak0, Bb);               \
        async16(Bg + (size_t)(bn + ar1) * Hq + k0s + ak1, Bb + 2048);        \
    } while (0)

    STAGE(0, 0);
    STAGE(1, 1);

#pragma unroll
    for (int t = 0; t < 16; ++t) {
        // drain my own stage(t); leave stage(t+1) in flight
        if (t < 15) asm volatile("s_waitcnt vmcnt(4)" ::: "memory");
        else        asm volatile("s_waitcnt vmcnt(0)" ::: "memory");
        __builtin_amdgcn_s_barrier();
        asm volatile("" ::: "memory");   // no LDS ops hoist above the barrier

        // issue next prefetch FIRST: slot (t+2)%3 == (t-1)%3 was fully read
        // at iter t-1 (trailing lgkmcnt(0)) before this barrier -> safe.
        if (t + 2 < 16) STAGE(t + 2, (t + 2) % 3);

        const unsigned short* Asb = &As[(t % 3) * 4096];
        const unsigned short* Bsb = &Bs[(t % 3) * 4096];
        bf16x8 af[4], bfr[4];
#pragma unroll
        for (int i = 0; i < 4; ++i)
            af[i] = *(const bf16x8*)&Asb[(size_t)(kq * 128 + wr * 64 + i * 16 + lr) * 8];
#pragma unroll
        for (int j = 0; j < 4; ++j)
            bfr[j] = *(const bf16x8*)&Bsb[(size_t)(kq * 128 + wc * 64 + j * 16 + lr) * 8];

#pragma unroll
        for (int i = 0; i < 4; ++i)
#pragma unroll
            for (int j = 0; j < 4; ++j)
                acc[i][j] = __builtin_amdgcn_mfma_f32_16x16x32_bf16(
                    af[i], bfr[j], acc[i][j], 0, 0, 0);

        // all my ds_reads complete before the next barrier lets anyone's
        // DMA overwrite this ring slot
        asm volatile("s_waitcnt lgkmcnt(0)" ::: "memory");
    }
#undef STAGE

    // ---------------- fused epilogue: e = exp(score + bias) -> bf16 ------
    if (tid < 128) rs[tid] = 0.f;
    __syncthreads();

    float bvv[4];
#pragma unroll
    for (int j = 0; j < 4; ++j)
        bvv[j] = bv[bn + wc * 64 + j * 16 + lr];

    // C/D layout: col = lane&15, row = (lane>>4)*4 + reg
#pragma unroll
    for (int i = 0; i < 4; ++i) {
        int lrow = wr * 64 + i * 16 + kq * 4;   // local row base of regs r=0..3
        float rsum[4] = {0.f, 0.f, 0.f, 0.f};
#pragma unroll
        for (int j = 0; j < 4; ++j) {
            int gc = bn + wc * 64 + j * 16 + lr;
#pragma unroll
            for (int r = 0; r < 4; ++r) {
                float v = __expf(acc[i][j][r] + bvv[j]);
                if (gc == 0) v = 0.f;   // scores[:,0] = -inf -> e = 0
                eb[(size_t)(bm + lrow + r) * Vq + gc] = __float2bfloat16(v);
                rsum[r] += v;
            }
        }
        // reduce over the 16 lanes (lr) of this kq group
#pragma unroll
        for (int off = 1; off < 16; off <<= 1) {
#pragma unroll
            for (int r = 0; r < 4; ++r)
                rsum[r] += __shfl_xor(rsum[r], off);
        }
        if (lr == 0) {
#pragma unroll
            for (int r = 0; r < 4; ++r)
                atomicAdd(&rs[lrow + r], rsum[r]);   // LDS atomic (wc pair)
        }
    }
    __syncthreads();
    if (tid < 128) partial[(size_t)nb * ROWS + bm + tid] = rs[tid];
}

// -------------------------------------------------------------------------
// K4: per-row finalize — one block per row:
//   1. sum e over vocab from per-nb partials (no global atomics)
//   2. vocab probs = bf16(e) * pgen/S, fused vocab argmax
//   3. source scatter-add + write + argmax
//   4. target scatter-add + write + argmax
//   5. combine -> predictions
__global__ __launch_bounds__(256)
void finalize(const __hip_bfloat16* __restrict__ e_bf,
              const float* __restrict__ partial,
              const float* __restrict__ p,
              const float* __restrict__ src_att, const int* __restrict__ sidx,
              const float* __restrict__ tgt_att, const int* __restrict__ tidx,
              float* __restrict__ out, float* __restrict__ pred) {
    int row = blockIdx.x;
    int tid = threadIdx.x;
    int b   = row >> 9;   // /512
    __shared__ float accs[TDVq];
    __shared__ float bs[256];
    __shared__ int   is_[256];
    __shared__ float sred[4];

    // --- phase 0: S = sum_e -------------------------------------------------
    float s = 0.f;
    for (int nb = tid; nb < NBLK; nb += 256)
        s += partial[(size_t)nb * ROWS + row];
    for (int off = 32; off > 0; off >>= 1) s += __shfl_down(s, off);
    if ((tid & 63) == 0) sred[tid >> 6] = s;
    __syncthreads();
    float S     = sred[0] + sred[1] + sred[2] + sred[3];
    float scale = p[row * 3 + 2] / S;   // pgen / sum(e)

    // --- phase 1: vocab probs + argmax --------------------------------------
    const ushort8* er = (const ushort8*)(e_bf + (size_t)row * Vq);
    float* orow = out + (size_t)row * OUTW;
    float4* ov  = (float4*)orow;
    float bm_ = -1.f; int bi = 0;       // e >= 0; col 0 is exactly 0
    for (int i = tid; i < Vq / 8; i += 256) {
        ushort8 v = er[i];
        float f[8];
#pragma unroll
        for (int k = 0; k < 8; ++k) f[k] = bf2f(v[k]);
#pragma unroll
        for (int k = 0; k < 8; ++k)
            if (f[k] > bm_) { bm_ = f[k]; bi = i * 8 + k; }
        float4 lo = {f[0] * scale, f[1] * scale, f[2] * scale, f[3] * scale};
        float4 hi = {f[4] * scale, f[5] * scale, f[6] * scale, f[7] * scale};
        ov[2 * i]     = lo;
        ov[2 * i + 1] = hi;
    }
    bs[tid] = bm_; is_[tid] = bi;
    __syncthreads();
    for (int st = 128; st > 0; st >>= 1) {
        if (tid < st) {
            float v2 = bs[tid + st]; int i2 = is_[tid + st];
            if (v2 > bs[tid] || (v2 == bs[tid] && i2 < is_[tid])) {
                bs[tid] = v2; is_[tid] = i2;
            }
        }
        __syncthreads();
    }
    float cv0 = bs[0] * scale; int ci0 = is_[0];
    __syncthreads();

    // --- phase 2: source copy distribution ----------------------------------
    for (int i = tid; i < SDVq; i += 256) accs[i] = 0.f;
    __syncthreads();
    {
        const float* arow = src_att + (size_t)row * Sq;
        const int*   ib   = sidx + b * Sq;
        for (int s2 = tid; s2 < Sq; s2 += 256)
            atomicAdd(&accs[ib[s2]], arow[s2]);
    }
    __syncthreads();
    {
        float pc = p[row * 3 + 0];
        float bm2 = -INFINITY; int bi2 = 0;
        for (int v = tid; v < SDVq; v += 256) {
            float val = accs[v] * pc;
            orow[Vq + v] = val;
            if (val > bm2) { bm2 = val; bi2 = v; }
        }
        bs[tid] = bm2; is_[tid] = bi2;
    }
    __syncthreads();
    for (int st = 128; st > 0; st >>= 1) {
        if (tid < st) {
            float v2 = bs[tid + st]; int i2 = is_[tid + st];
            if (v2 > bs[tid] || (v2 == bs[tid] && i2 < is_[tid])) {
                bs[tid] = v2; is_[tid] = i2;
            }
        }
        __syncthreads();
    }
    float cv1 = bs[0]; int ci1 = Vq + is_[0];
    __syncthreads();

    // --- phase 3: target copy distribution ----------------------------------
    for (int i = tid; i < TDVq; i += 256) accs[i] = 0.f;
    __syncthreads();
    {
        const float* arow = tgt_att + (size_t)row * TDVq;
        const int*   ib   = tidx + b * TDVq;
        for (int s2 = tid; s2 < TDVq; s2 += 256)
            atomicAdd(&accs[ib[s2]], arow[s2]);
    }
    __syncthreads();
    {
        float pc = p[row * 3 + 1];
        float bm2 = -INFINITY; int bi2 = 0;
        for (int v = tid; v < TDVq; v += 256) {
            float val = accs[v] * pc;
            orow[Vq + SDVq + v] = val;
            if (val > bm2) { bm2 = val; bi2 = v; }
        }
        bs[tid] = bm2; is_[tid] = bi2;
    }
    __syncthreads();
    for (int st = 128; st > 0; st >>= 1) {
        if (tid < st) {
            float v2 = bs[tid + st]; int i2 = is_[tid + st];
            if (v2 > bs[tid] || (v2 == bs[tid] && i2 < is_[tid])) {
                bs[tid] = v2; is_[tid] = i2;
            }
        }
        __syncthreads();
    }

    // --- phase 4: combine (first-index-wins on ties via region order) -------
    if (tid == 0) {
        float cv2 = bs[0]; int ci2 = Vq + SDVq + is_[0];
        float v = cv0; int i = ci0;
        if (cv1 > v) { v = cv1; i = ci1; }
        if (cv2 > v) { v = cv2; i = ci2; }
        pred[row] = (float)i;
    }
}

// -------------------------------------------------------------------------
extern "C" void kernel_launch(void* const* d_in, const int* in_sizes, int n_in,
                              void* d_out, int out_size, void* d_ws, size_t ws_size,
                              hipStream_t stream) {
    const float* hiddens = (const float*)d_in[0];
    const float* Wp      = (const float*)d_in[1];
    const float* bp      = (const float*)d_in[2];
    const float* Wv      = (const float*)d_in[3];
    const float* bv      = (const float*)d_in[4];
    const float* src_att = (const float*)d_in[5];
    const float* src_map = (const float*)d_in[6];
    const float* tgt_att = (const float*)d_in[7];
    const float* tgt_map = (const float*)d_in[8];

    float* out  = (float*)d_out;
    float* pred = out + (size_t)ROWS * OUTW;

    // workspace layout (bytes)
    char* ws = (char*)d_ws;
    float* p_ws    = (float*)(ws);                        // 24 KB
    int*   sidx    = (int*)(ws + (24 << 10));             // 8 KB
    int*   tidx    = (int*)(ws + (32 << 10));             // 8 KB
    float* partial = (float*)(ws + (64 << 10));           // 250*2048*4 ~ 2 MB
    __hip_bfloat16* A_bf = (__hip_bfloat16*)(ws + (64 << 10) + (2 << 20));   // 2 MB
    __hip_bfloat16* e_bf = (__hip_bfloat16*)(ws + (64 << 10) + (4 << 20));   // 125 MB
    __hip_bfloat16* Wt   = (__hip_bfloat16*)(ws + (64 << 10) + (4 << 20) + (128 << 20)); // 32.75 MB

    // conversions
    convert_a<<<ROWS * Hq / 4 / 256, 256, 0, stream>>>(hiddens, A_bf);
    {
        dim3 tg(Vq / 32, Hq / 32);   // (1000, 16)
        dim3 tb(32, 8);
        transpose_wv<<<tg, tb, 0, stream>>>(Wv, Wt);
    }

    // gate probabilities + one-hot indices
    compute_p<<<ROWS, 64, 0, stream>>>(hiddens, Wp, bp, p_ws);
    extract_idx<<<Bq * Sq, 64, 0, stream>>>(src_map, SDVq, sidx);
    extract_idx<<<Bq * Tq, 64, 0, stream>>>(tgt_map, TDVq, tidx);

    // GEMM (pipelined, XCD-swizzled) with fused exp+bias epilogue;
    // writes bf16 e + non-atomic per-nb row-sum partials.
    gemm_mfma<<<(ROWS / 128) * NBLK, 256, 0, stream>>>(A_bf, Wt, bv, e_bf, partial);

    // fused tail: normalize+write vocab, both scatters, predictions
    finalize<<<ROWS, 256, 0, stream>>>(e_bf, partial, p_ws,
                                       src_att, sidx, tgt_att, tidx, out, pred);
}